// Round 5
// baseline (92.133 us; speedup 1.0000x reference)
//
#include <hip/hip_runtime.h>
#include <math.h>

// B=256; bilinear upsample 64/32/16 -> 256x256 (align_corners=True), sum -> maps;
// 5x5 gaussian blur (sigma=4, reflect); per-sample max -> scores.
//
// v6 = v5 (LDS x-interp rows, no per-thread rolling state -> no spill) with
// residency fixed: QB=16 (16-row strips, 4 rows/wave).
//   - LDS 18176 B (v5: 26368) -> 8 blocks/CU (wave cap) = 32 waves/CU hw max,
//     grid 4096 = 16 work-blocks/CU pipelined 8 deep
//   - serial chain per wave: 8 samples (v5: 12); redundancy 2.0x, VALU issue
//     floor ~7 us still < ~12 us memory floor
//   - per block: stage raw source-row slices (float4), x-interp scales 1,2 into
//     xr1/xr2, barrier, x-interp scale 0 into xr0 (aliases dead s1r/s2r), barrier
//   - per output row: wave-uniform (y,fy) per scale + 6 aligned float4 LDS reads
//   - vertical 5-tap in registers; horizontal 5-tap via in-wave __shfl
//   - per-wave shuffle-reduce max -> part[bid*4+wv]
// Kernel 2: partials -> scores (deterministic).

static constexpr int W  = 256;
static constexpr int QB = 16;            // blocks per sample (16 rows each)

__device__ __forceinline__ int reflect256(int i) {
    if (i < 0) i = -i;
    if (i > 255) i = 510 - i;
    return i;
}

__global__ __launch_bounds__(256, 4) void fused_kernel(
    const float* __restrict__ in0,   // [B,64,64]
    const float* __restrict__ in1,   // [B,32,32]
    const float* __restrict__ in2,   // [B,16,16]
    float* __restrict__ part,        // [B*QB*4] per-wave partial maxes
    float* __restrict__ maps)        // [B,256,256]
{
    const int t   = threadIdx.x;
    const int q   = t & 63;                                      // lane = column quad
    const int wv  = __builtin_amdgcn_readfirstlane(t >> 6);      // wave id (SGPR)
    const int bid = blockIdx.x;
    const int b   = bid >> 4;
    const int r0  = (bid & 15) * 16;
    const int rw0 = r0 + wv * 4;                                 // wave's first output row
    const int c0  = q * 4;

    // ---- source-row slice bounds (block-uniform); strip+halo spans <= 20 rows ----
    const int rlo = max(r0 - 2, 0);
    const int rhi = min(r0 + 17, 255);
    const int y0lo = (rlo * 63) / 255;
    const int y1lo = (rlo * 31) / 255;
    const int y2lo = (rlo * 15) / 255;
    const int y0hi = min((rhi * 63) / 255 + 1, 63);
    const int y1hi = min((rhi * 31) / 255 + 1, 31);
    const int y2hi = min((rhi * 15) / 255 + 1, 15);
    const int n0 = y0hi - y0lo + 1;      // <= 7
    const int n1 = y1hi - y1lo + 1;      // <= 5
    const int n2 = y2hi - y2lo + 1;      // <= 4

    // ---- LDS layout (floats), 4544 * 4 = 18176 B -> 8 blocks/CU (wave cap) ----
    // [0,448)      s0r raw 7x64
    // [448,608)    s1r raw 5x32   (dead after phase A)
    // [608,672)    s2r raw 4x16   (dead after phase A)
    // [448,2240)   xr0 7x256      (phase B output, aliases s1r/s2r)
    // [2240,3520)  xr1 5x256
    // [3520,4544)  xr2 4x256
    __shared__ float lds[4544];
    float* const s0r = lds;
    float* const s1r = lds + 448;
    float* const s2r = lds + 608;
    float* const xr0 = lds + 448;
    float* const xr1 = lds + 2240;
    float* const xr2 = lds + 3520;

    // ---- stage raw slices (float4, coalesced) ----
    {
        const float4* g0 = (const float4*)(in0 + (size_t)b * 4096 + y0lo * 64);
        const float4* g1 = (const float4*)(in1 + (size_t)b * 1024 + y1lo * 32);
        const float4* g2 = (const float4*)(in2 + (size_t)b * 256  + y2lo * 16);
        if (t < n0 * 16) ((float4*)s0r)[t] = g0[t];
        if (t < n1 * 8)  ((float4*)s1r)[t] = g1[t];
        if (t < n2 * 4)  ((float4*)s2r)[t] = g2[t];
    }
    __syncthreads();

    const float inv255 = 1.0f / 255.0f;

    // ---- phase A: x-interp scales 1,2 (one output column per thread) ----
    {
        int ix = t * 31; int xa = ix / 255; float fx = (float)(ix - 255 * xa) * inv255; int xb = min(xa + 1, 31);
        for (int r = 0; r < n1; ++r) {
            float a = s1r[r * 32 + xa], bv = s1r[r * 32 + xb];
            xr1[r * 256 + t] = a + fx * (bv - a);
        }
        ix = t * 15; xa = ix / 255; fx = (float)(ix - 255 * xa) * inv255; xb = min(xa + 1, 15);
        for (int r = 0; r < n2; ++r) {
            float a = s2r[r * 16 + xa], bv = s2r[r * 16 + xb];
            xr2[r * 256 + t] = a + fx * (bv - a);
        }
    }
    __syncthreads();                      // s1r/s2r dead; xr0 may overwrite them

    // ---- phase B: x-interp scale 0 (s0r disjoint from xr0) ----
    {
        int ix = t * 63; int xa = ix / 255; float fx = (float)(ix - 255 * xa) * inv255; int xb = min(xa + 1, 63);
        for (int r = 0; r < n0; ++r) {
            float a = s0r[r * 64 + xa], bv = s0r[r * 64 + xb];
            xr0[r * 256 + t] = a + fx * (bv - a);
        }
    }
    __syncthreads();

    // ---- per-row sampler: wave-uniform (y,fy) per scale + 6 aligned float4 LDS reads ----
    auto sample = [&](int rn, float* o) {
        const int ry = reflect256(rn);
        int iy = ry * 63; int ya = iy / 255; float w0 = (float)(iy - 255 * ya) * inv255; int ya1 = min(ya + 1, 63);
        int ib = ry * 31; int yb = ib / 255; float w1 = (float)(ib - 255 * yb) * inv255; int yb1 = min(yb + 1, 31);
        int ic = ry * 15; int yc = ic / 255; float w2 = (float)(ic - 255 * yc) * inv255; int yc1 = min(yc + 1, 15);
        const float4 l0 = *(const float4*)(xr0 + (ya  - y0lo) * 256 + c0);
        const float4 h0 = *(const float4*)(xr0 + (ya1 - y0lo) * 256 + c0);
        const float4 l1 = *(const float4*)(xr1 + (yb  - y1lo) * 256 + c0);
        const float4 h1 = *(const float4*)(xr1 + (yb1 - y1lo) * 256 + c0);
        const float4 l2 = *(const float4*)(xr2 + (yc  - y2lo) * 256 + c0);
        const float4 h2 = *(const float4*)(xr2 + (yc1 - y2lo) * 256 + c0);
        o[0] = (l0.x + w0 * (h0.x - l0.x)) + (l1.x + w1 * (h1.x - l1.x)) + (l2.x + w2 * (h2.x - l2.x));
        o[1] = (l0.y + w0 * (h0.y - l0.y)) + (l1.y + w1 * (h1.y - l1.y)) + (l2.y + w2 * (h2.y - l2.y));
        o[2] = (l0.z + w0 * (h0.z - l0.z)) + (l1.z + w1 * (h1.z - l1.z)) + (l2.z + w2 * (h2.z - l2.z));
        o[3] = (l0.w + w0 * (h0.w - l0.w)) + (l1.w + w1 * (h1.w - l1.w)) + (l2.w + w2 * (h2.w - l2.w));
    };

    // ---- gaussian weights (ksize=5, sigma=4) ----
    const float e1 = expf(-1.0f / 32.0f);
    const float e2 = expf(-4.0f / 32.0f);
    const float nrm = 1.0f + 2.0f * e1 + 2.0f * e2;
    const float gwc = 1.0f / nrm, gwa = e1 / nrm, gwb = e2 / nrm;

    // ---- prime 4-row blur window (reflect handles rw0==0) ----
    float m0[4], m1[4], m2[4], m3[4], mn[4];
    sample(rw0 - 2, m0);
    sample(rw0 - 1, m1);
    sample(rw0,     m2);
    sample(rw0 + 1, m3);

    float* __restrict__ mpr = maps + ((size_t)b * W + (size_t)rw0) * W + c0;
    *(float4*)(mpr)     = make_float4(m2[0], m2[1], m2[2], m2[3]);
    *(float4*)(mpr + W) = make_float4(m3[0], m3[1], m3[2], m3[3]);

    float gmax = -INFINITY;

#pragma unroll
    for (int i = 0; i < 4; ++i) {
        sample(rw0 + 2 + i, mn);         // reflect handles rows 256/257 (last strip)

        if (i < 2)                       // rows rw0+2, rw0+3 are ours
            *(float4*)(mpr + (size_t)(2 + i) * W) = make_float4(mn[0], mn[1], mn[2], mn[3]);

        // vertical 5-tap for blur row rw0+i (in registers)
        float vr0 = gwb * (m0[0] + mn[0]) + gwa * (m1[0] + m3[0]) + gwc * m2[0];
        float vr1 = gwb * (m0[1] + mn[1]) + gwa * (m1[1] + m3[1]) + gwc * m2[1];
        float vr2 = gwb * (m0[2] + mn[2]) + gwa * (m1[2] + m3[2]) + gwc * m2[2];
        float vr3 = gwb * (m0[3] + mn[3]) + gwa * (m1[3] + m3[3]) + gwc * m2[3];
#pragma unroll
        for (int k = 0; k < 4; ++k) { m0[k] = m1[k]; m1[k] = m2[k]; m2[k] = m3[k]; m3[k] = mn[k]; }

        // horizontal 5-tap: neighbor-quad edge columns via in-wave shuffles
        float az = __shfl_up(vr2, 1);        // col c0-2 from left lane
        float aw = __shfl_up(vr3, 1);        // col c0-1
        float cx = __shfl_down(vr0, 1);      // col c0+4 from right lane
        float cy = __shfl_down(vr1, 1);      // col c0+5
        float a2 = (q == 0)  ? vr2 : az;     // reflect at col 0
        float a3 = (q == 0)  ? vr1 : aw;
        float c4 = (q == 63) ? vr2 : cx;     // reflect at col 255
        float c5 = (q == 63) ? vr1 : cy;
        float o0 = gwc * vr0 + gwa * (a3 + vr1)  + gwb * (a2 + vr2);
        float o1 = gwc * vr1 + gwa * (vr0 + vr2) + gwb * (a3 + vr3);
        float o2 = gwc * vr2 + gwa * (vr1 + vr3) + gwb * (vr0 + c4);
        float o3 = gwc * vr3 + gwa * (vr2 + c4)  + gwb * (vr1 + c5);
        gmax = fmaxf(gmax, fmaxf(fmaxf(o0, o1), fmaxf(o2, o3)));
    }

    // ---- per-wave max -> partial (no extra barrier) ----
#pragma unroll
    for (int off = 32; off > 0; off >>= 1)
        gmax = fmaxf(gmax, __shfl_down(gmax, off));
    if (q == 0) part[bid * 4 + wv] = gmax;
}

__global__ void reduce_kernel(const float* __restrict__ part,
                              float* __restrict__ scores, int B) {
    int i = blockIdx.x * blockDim.x + threadIdx.x;
    if (i < B) {
        const float4* p = (const float4*)(part + 64 * i);   // QB*4 = 64 partials
        float m = -INFINITY;
#pragma unroll
        for (int k = 0; k < 16; ++k) {
            float4 v = p[k];
            m = fmaxf(m, fmaxf(fmaxf(v.x, v.y), fmaxf(v.z, v.w)));
        }
        scores[i] = m;
    }
}

extern "C" void kernel_launch(void* const* d_in, const int* in_sizes, int n_in,
                              void* d_out, int out_size, void* d_ws, size_t ws_size,
                              hipStream_t stream) {
    const float* in0 = (const float*)d_in[0];
    const float* in1 = (const float*)d_in[1];
    const float* in2 = (const float*)d_in[2];
    const int B = in_sizes[0] / (64 * 64);

    float* scores = (float*)d_out;
    float* maps   = (float*)d_out + B;
    float* part   = (float*)d_ws;          // B*QB*4 floats, fully rewritten each call

    hipLaunchKernelGGL(fused_kernel, dim3(B * QB), dim3(256), 0, stream,
                       in0, in1, in2, part, maps);
    hipLaunchKernelGGL(reduce_kernel, dim3((B + 255) / 256), dim3(256), 0, stream,
                       part, scores, B);
}